// Round 6
// baseline (172.520 us; speedup 1.0000x reference)
//
#include <hip/hip_runtime.h>
#include <hip/hip_bf16.h>

// scores[b,t] = sum_u tanh((source@W1)[b,u] + (target@W2)[b,t,u]) * a[u]
// B=64 T=8192 D=256 U=128. Memory-bound: 537MB target read; ~86us floor at 6.3TB/s.
// Round 6: linear-stream staging. R5 skew HURT (108->120us) => DRAM page locality,
// not channel phase, is the cost; register-direct frag loads are inherently
// column-major in time (16 rows x 256B per batch). Now: target tiles staged to LDS
// with fill-identical linear loads (4 x 8KB contiguous per 512-thr block), bf16
// convert, double-buffered; W2 lives in REGISTERS (64 VGPR of frags per lane,
// u-quarter per wave) so the K-loop is 1 ds_read_b128 + 2 MFMA per k-chunk.

#define B_ 64
#define T_ 8192
#define D_ 256
#define U_ 128
#define LDSW 264      // padded bf16 row stride: frag reads 8 lanes/bank-quad (floor)
#define TROWS 32      // rows per tile
#define NTILES 32     // 1024 rows per block

typedef __attribute__((ext_vector_type(8))) short bf16x8;
typedef __attribute__((ext_vector_type(4))) short bf16x4;
typedef __attribute__((ext_vector_type(4))) float f32x4;

__device__ __forceinline__ short f2bf(float f) {
    unsigned u = __builtin_bit_cast(unsigned, f);
    u += 0x7fffu + ((u >> 16) & 1u);   // RTNE
    return (short)(u >> 16);
}

__device__ __forceinline__ float fast_tanh(float x) {
    float e = __expf(2.0f * x);
    return 1.0f - 2.0f * __builtin_amdgcn_rcpf(e + 1.0f);
}

__device__ __forceinline__ bf16x4 cvt4(const float4& a) {
    union { __hip_bfloat162 h[2]; bf16x4 v; } u;
    u.h[0] = __float22bfloat162_rn(make_float2(a.x, a.y));
    u.h[1] = __float22bfloat162_rn(make_float2(a.z, a.w));
    return u.v;
}

__global__ __launch_bounds__(512)
__attribute__((amdgpu_waves_per_eu(4, 4)))
void additive_attn_kernel(
        const float* __restrict__ target,
        const float* __restrict__ source,
        const float* __restrict__ W1,
        const float* __restrict__ W2,
        const float* __restrict__ attn,
        float* __restrict__ out) {
    // two 32-row tile buffers (double-buffered target staging)
    __shared__ __attribute__((aligned(16))) short lds_tile[2][TROWS * LDSW]; // 33.8KB
    __shared__ float  lds_red[512];
    __shared__ __attribute__((aligned(16))) float2 lds_sa[U_];   // {s_u, a_u}
    __shared__ float  lds_part[2][4][TROWS];                     // u-quarter partials

    const int tid  = threadIdx.x;
    const int bx   = blockIdx.x;
    const int b    = bx >> 3;            // 8 blocks per batch element
    const int tb   = (bx & 7) << 10;     // 1024 rows per block

    const int lane = tid & 63;
    const int wave = tid >> 6;           // 0..7
    const int rg   = wave & 1;           // row-group: rows rg*16 .. +16
    const int uq   = wave >> 1;          // u-quarter: u in [uq*32, uq*32+32)
    const int c    = lane & 15;
    const int g    = lane >> 4;

    const float* tgt  = target + ((size_t)b * T_ + tb) * D_;
    float*       outp = out + (size_t)b * T_ + tb;

    float4 pl0, pl1, pl2, pl3;   // one tile's payload: 4 x 8KB linear chunks

#define LOADT(I) do {                                                         \
    const float* p_ = tgt + (size_t)(I) * (TROWS * D_) + tid * 4;             \
    pl0 = *(const float4*)(p_);        pl1 = *(const float4*)(p_ + 2048);     \
    pl2 = *(const float4*)(p_ + 4096); pl3 = *(const float4*)(p_ + 6144);     \
} while (0)

    // row = k*8 + (tid>>6), col = 4*(tid&63)  (matches LOADT's linear mapping)
#define STORET(BP) do {                                                       \
    short* d_ = &lds_tile[BP][(tid >> 6) * LDSW + 4 * (tid & 63)];            \
    *(bf16x4*)(d_ + 0 * 8 * LDSW) = cvt4(pl0);                                \
    *(bf16x4*)(d_ + 1 * 8 * LDSW) = cvt4(pl1);                                \
    *(bf16x4*)(d_ + 2 * 8 * LDSW) = cvt4(pl2);                                \
    *(bf16x4*)(d_ + 3 * 8 * LDSW) = cvt4(pl3);                                \
} while (0)

    LOADT(0);   // tile 0 in flight over the whole prologue

    // --- W2 frags -> registers. Lane (c,g) of wave uq holds, for kk=0..7,j=0..1:
    //     u = uq*32+16j+c, k = kk*32+g*8+e.  W2 (512KB fp32) is L2-resident. ---
    bf16x8 wf[8][2];
    {
        const float* wbase = W2 + (size_t)(g * 8) * U_ + uq * 32 + c;
        #pragma unroll
        for (int kk = 0; kk < 8; ++kk)
            #pragma unroll
            for (int j = 0; j < 2; ++j) {
                const float* wp = wbase + (size_t)(kk * 32) * U_ + 16 * j;
                bf16x8 v;
                #pragma unroll
                for (int e = 0; e < 8; ++e) v[e] = f2bf(wp[(size_t)e * U_]);
                wf[kk][j] = v;
            }
    }

    // --- s[u] = (source[b] @ W1)[u], 4-way D split over 512 threads ---
    {
        const float* src = source + b * D_;
        const int u    = tid & (U_ - 1);
        const int part = tid >> 7;
        float acc = 0.f;
        #pragma unroll 8
        for (int d = part * 64; d < part * 64 + 64; ++d)
            acc = fmaf(src[d], W1[(size_t)d * U_ + u], acc);
        lds_red[tid] = acc;
    }
    __syncthreads();
    if (tid < U_)
        lds_sa[tid] = make_float2(
            lds_red[tid] + lds_red[tid + 128] + lds_red[tid + 256] + lds_red[tid + 384],
            attn[tid]);
    STORET(0);      // tile 0 -> buf0 (waits vmcnt for tile0 loads)
    LOADT(1);       // tile 1 in flight
    __syncthreads();

    // --- main loop: stage tile i+1 -> buf[1-p], compute tile i from buf[p] ---
#define BODY(I, P) do {                                                       \
    if ((I) < NTILES - 1) STORET(1 - (P));                                    \
    if ((I) < NTILES - 2) LOADT((I) + 2);                                     \
    {                                                                         \
        const short* trow = &lds_tile[P][(rg * 16 + c) * LDSW + g * 8];       \
        f32x4 a0 = (f32x4){0.f, 0.f, 0.f, 0.f};                               \
        f32x4 a1 = (f32x4){0.f, 0.f, 0.f, 0.f};                               \
        _Pragma("unroll")                                                     \
        for (int kk = 0; kk < 8; ++kk) {                                      \
            bf16x8 tf = *(const bf16x8*)(trow + kk * 32);                     \
            a0 = __builtin_amdgcn_mfma_f32_16x16x32_bf16(wf[kk][0], tf, a0, 0, 0, 0); \
            a1 = __builtin_amdgcn_mfma_f32_16x16x32_bf16(wf[kk][1], tf, a1, 0, 0, 0); \
        }                                                                     \
        float sc = 0.f;                                                       \
        {                                                                     \
            const float4 sa01 = *(const float4*)&lds_sa[uq * 32 + 4 * g];     \
            const float4 sa23 = *(const float4*)&lds_sa[uq * 32 + 4 * g + 2]; \
            sc += fast_tanh(a0[0] + sa01.x) * sa01.y;                         \
            sc += fast_tanh(a0[1] + sa01.z) * sa01.w;                         \
            sc += fast_tanh(a0[2] + sa23.x) * sa23.y;                         \
            sc += fast_tanh(a0[3] + sa23.z) * sa23.w;                         \
        }                                                                     \
        {                                                                     \
            const float4 sa01 = *(const float4*)&lds_sa[uq * 32 + 16 + 4 * g];\
            const float4 sa23 = *(const float4*)&lds_sa[uq * 32 + 18 + 4 * g];\
            sc += fast_tanh(a1[0] + sa01.x) * sa01.y;                         \
            sc += fast_tanh(a1[1] + sa01.z) * sa01.w;                         \
            sc += fast_tanh(a1[2] + sa23.x) * sa23.y;                         \
            sc += fast_tanh(a1[3] + sa23.z) * sa23.w;                         \
        }                                                                     \
        sc += __shfl_xor(sc, 16);                                             \
        sc += __shfl_xor(sc, 32);                                             \
        if (lane < 16) lds_part[P][uq][rg * 16 + lane] = sc;                  \
    }                                                                         \
    if ((I) > 0 && tid < TROWS)                                               \
        outp[((I) - 1) * TROWS + tid] =                                       \
            lds_part[1 - (P)][0][tid] + lds_part[1 - (P)][1][tid] +           \
            lds_part[1 - (P)][2][tid] + lds_part[1 - (P)][3][tid];            \
    __syncthreads();                                                          \
} while (0)

    for (int ii = 0; ii < NTILES; ii += 2) {
        BODY(ii, 0);
        BODY(ii + 1, 1);
    }
    // tail: combine tile 31 partials (in lds_part[1])
    if (tid < TROWS)
        outp[(NTILES - 1) * TROWS + tid] =
            lds_part[1][0][tid] + lds_part[1][1][tid] +
            lds_part[1][2][tid] + lds_part[1][3][tid];

#undef LOADT
#undef STORET
#undef BODY
}

extern "C" void kernel_launch(void* const* d_in, const int* in_sizes, int n_in,
                              void* d_out, int out_size, void* d_ws, size_t ws_size,
                              hipStream_t stream) {
    const float* target = (const float*)d_in[0];
    const float* source = (const float*)d_in[1];
    const float* W1     = (const float*)d_in[2];
    const float* W2     = (const float*)d_in[3];
    const float* attn   = (const float*)d_in[4];
    float* out = (float*)d_out;

    dim3 grid(B_ * (T_ / 1024));   // 512 blocks = 2 per CU
    dim3 block(512);
    hipLaunchKernelGGL(additive_attn_kernel, grid, block, 0, stream,
                       target, source, W1, W2, attn, out);
}